// Round 8
// baseline (163.631 us; speedup 1.0000x reference)
//
#include <hip/hip_runtime.h>
#include <hip/hip_bf16.h>
#include <stdint.h>

// ModalAttention: B=2, T=2048, C=1024, H=16, D=64, N_WORLDS=4
// ESTABLISHED: inputs fp32, accessibility int32, OUTPUT fp32, ws >= 40 MB.
// Round 20: qkv -> 256x256 tile / 512 thr / 8 waves / BK=32 dbuf (64KB LDS).
//  r19 PASSED 159.2us (qkv 44.6, operand-swap epilogues). qkv at 578 TF is
//  at the 128^2/2-phase structural ceiling (m99-m141 precedent: dbuf/vmcnt
//  neutral there). Doubling tile -> 2x MFMA per staged byte, half the
//  barriers per FLOP. Grid 192 blocks (QK 8x16 + V 16x4) = 1 round on 256
//  CUs. Epilogues = r19-proven mappings at 256-row scale (vshufX).
//  Same k-order -> bit-identical. attn/proj/cvt/fallback untouched.

typedef __attribute__((ext_vector_type(8))) __bf16   bf16x8;
typedef __attribute__((ext_vector_type(4))) float    f32x4;
typedef __attribute__((ext_vector_type(8))) ushort   ushort8;

__device__ __forceinline__ ushort f2bf(float x) {
    uint32_t u = __float_as_uint(x);
    return (ushort)((u + 0x7fffu + ((u >> 16) & 1u)) >> 16);
}
__device__ __forceinline__ float sentinel(float v, float s) {
    return (fabsf(v) < 1e30f) ? v : s;
}
__device__ __forceinline__ f32x4 mfma16(bf16x8 a, bf16x8 b, f32x4 c) {
    return __builtin_amdgcn_mfma_f32_16x16x32_bf16(a, b, c, 0, 0, 0);
}
__device__ __forceinline__ ushort2 pk2(float a, float b) {
    __hip_bfloat162 h = __float22bfloat162_rn(make_float2(a, b));
    union { __hip_bfloat162 h; ushort2 u; } c; c.h = h; return c.u;
}
__device__ __forceinline__ ushort4 cvt4(float4 v) {
    ushort2 lo = pk2(v.x, v.y), hi = pk2(v.z, v.w);
    ushort4 r; r.x = lo.x; r.y = lo.y; r.z = hi.x; r.w = hi.y; return r;
}
__device__ __forceinline__ ushort4 cvt4s(float4 v, float s) {
    ushort2 lo = pk2(v.x * s, v.y * s), hi = pk2(v.z * s, v.w * s);
    ushort4 r; r.x = lo.x; r.y = lo.y; r.z = hi.x; r.w = hi.y; return r;
}
__device__ __forceinline__ float fexp2(float x) {
#if __has_builtin(__builtin_amdgcn_exp2f)
    return __builtin_amdgcn_exp2f(x);
#else
    return exp2f(x);
#endif
}
__device__ __forceinline__ void gld16(const ushort* g, ushort* l) {
    auto* g1 = reinterpret_cast<const __attribute__((address_space(1))) uint32_t*>(
        reinterpret_cast<uintptr_t>(g));
    auto* l3 = reinterpret_cast<__attribute__((address_space(3))) uint32_t*>(
        reinterpret_cast<uintptr_t>(l));
    __builtin_amdgcn_global_load_lds(g1, l3, 16, 0, 0);
}

// swizzled element-offset of 8-elem chunk `ch` in row `row` of a 64-col tile
__device__ __forceinline__ int swz(int row, int ch) {
    return row * 64 + ((ch ^ (row & 7)) * 8);
}

// world-permuted token index: t -> (t%4)*512 + t/4
__device__ __forceinline__ int wperm(int ts) {
    return ((ts & 3) << 9) | (ts >> 2);
}

// V A-tile row shuffle on [0,128): r -> 4*(r&31) + (r>>5)  (r16 epilogue)
__device__ __forceinline__ int vshuf(int r) {
    return ((r & 31) << 2) | (r >> 5);
}
// V A-tile row shuffle on [0,256): r -> 4*(r&63) + (r>>6)  (256-tile variant)
__device__ __forceinline__ int vshufX(int r) {
    return ((r & 63) << 2) | (r >> 6);
}

#define QSCALE 0.1803368801111244f   // 1/sqrt(64) * log2(e)

// ---------------------------------------------------------------------------
// Prepass: fp32 -> bf16 (x, Wq*QSCALE, Wk, Wv, Wp).
// ---------------------------------------------------------------------------
__global__ __launch_bounds__(256) void cvt_prepass(
        const float* __restrict__ x,  const float* __restrict__ Wq,
        const float* __restrict__ Wk, const float* __restrict__ Wv,
        const float* __restrict__ Wp,
        ushort* __restrict__ xb,  ushort* __restrict__ wqb,
        ushort* __restrict__ wkb, ushort* __restrict__ wvb,
        ushort* __restrict__ wpb)
{
    int gid = blockIdx.x;
    const float* src; ushort* dst; float sc = 1.0f; int boff;
    if (gid < 4096)      { src = x;  dst = xb;  boff = gid; }
    else if (gid < 5120) { src = Wq; dst = wqb; boff = gid - 4096; sc = QSCALE; }
    else if (gid < 6144) { src = Wk; dst = wkb; boff = gid - 5120; }
    else if (gid < 7168) { src = Wv; dst = wvb; boff = gid - 6144; }
    else                 { src = Wp; dst = wpb; boff = gid - 7168; }
    size_t idx = (size_t)boff * 1024 + threadIdx.x * 4;
    float4 v = *(const float4*)&src[idx];
    *(ushort4*)&dst[idx] = cvt4s(v, sc);
}

// ---------------------------------------------------------------------------
// bf16 fused QKV GEMM, 256x256 tile, 512 thr / 8 waves, BK=32, dbuf 64KB.
// grid 192: bid<128 -> Q/K (blkM=bid&7 channel-tile over [Wq;Wk], blkN=bid>>3
// token-tile); bid>=128 -> V (token-tile x channel-tile, A rows vshufX'd).
// Per wave: 128(M) x 64(N) output, acc[8][4]; 32 MFMA vs 4 gld16/thr/K-step.
// ---------------------------------------------------------------------------
__global__ __launch_bounds__(512, 2) void gemm_qkv_b(
        const ushort* __restrict__ xb,
        const ushort* __restrict__ wqb, const ushort* __restrict__ wkb,
        const ushort* __restrict__ wvb,
        ushort* __restrict__ Cq, ushort* __restrict__ Ck,
        ushort* __restrict__ Cv)
{
    __shared__ ushort As[2][256 * 32];
    __shared__ ushort Bs[2][256 * 32];

    const int tid  = threadIdx.x;
    const int lane = tid & 63;
    const int wave = tid >> 6;          // 0..7
    const int quad = lane >> 4;
    const int l15  = lane & 15;
    const int wm2  = wave >> 2;         // 0..1: M-half (128 rows)
    const int wn4  = wave & 3;          // 0..3: N-quarter (64 cols)

    const int bid = blockIdx.x;
    const bool isV = bid >= 128;
    int tokb, chO;                       // chO: channel base of output tile
    const ushort* __restrict__ Aw;       // W panel base (A for QK, B for V)
    ushort* __restrict__ C;
    if (!isV) {
        const int blkM = bid & 7;        // channel tile over concat [Wq;Wk]
        const int blkN = bid >> 3;       // token tile
        tokb = blkN * 256;
        const int chb2 = blkM * 256;     // [0,2048)
        chO  = chb2 & 1023;
        Aw = (blkM < 4) ? (wqb + (size_t)chb2 * 1024)
                        : (wkb + (size_t)(chb2 - 1024) * 1024);
        C  = (blkM < 4) ? Cq : Ck;
    } else {
        const int v = bid - 128;
        tokb = (v & 15) * 256;
        chO  = (v >> 4) * 256;
        Aw = wvb + (size_t)chO * 1024;
        C  = Cv;
    }

    // stage K-step kt (32 cols) into buf: A 256x32 + B 256x32, 4 gld16/thr.
    auto stage = [&](int kt, int buf) {
        const int kcol = kt * 32;
        #pragma unroll
        for (int j = 0; j < 2; ++j) {
            int ci = j * 512 + tid;
            int r  = ci >> 2;
            int qc = (((ci & 3) ^ (r & 3) ^ ((r >> 2) & 3))) * 8;
            const ushort* asrc = isV ? &xb[(size_t)(tokb + vshufX(r)) * 1024]
                                     : &Aw[(size_t)r * 1024];
            const ushort* bsrc = isV ? &Aw[(size_t)r * 1024]
                                     : &xb[(size_t)(tokb + r) * 1024];
            gld16(&asrc[kcol + qc], &As[buf][ci * 8]);
            gld16(&bsrc[kcol + qc], &Bs[buf][ci * 8]);
        }
    };

    f32x4 acc[8][4] = {};

    stage(0, 0);
    for (int t = 0; t < 32; ++t) {
        const int cur = t & 1;
        __syncthreads();                  // buf[cur] staged; prev reads done
        if (t < 31) stage(t + 1, cur ^ 1);

        bf16x8 af[8], bf[4];
        #pragma unroll
        for (int i = 0; i < 8; ++i) {
            int row = wm2 * 128 + i * 16 + l15;
            int pos = quad ^ (row & 3) ^ ((row >> 2) & 3);
            af[i] = *(const bf16x8*)&As[cur][row * 32 + pos * 8];
        }
        #pragma unroll
        for (int tt = 0; tt < 4; ++tt) {
            int row = wn4 * 64 + tt * 16 + l15;
            int pos = quad ^ (row & 3) ^ ((row >> 2) & 3);
            bf[tt] = *(const bf16x8*)&Bs[cur][row * 32 + pos * 8];
        }
        #pragma unroll
        for (int i = 0; i < 8; ++i)
            #pragma unroll
            for (int tt = 0; tt < 4; ++tt)
                acc[i][tt] = mfma16(af[i], bf[tt], acc[i][tt]);
    }

    if (!isV) {
        // Q/K -> (b,h,t',d): D row = channel (r spans 4 consecutive d).
        #pragma unroll
        for (int i = 0; i < 8; ++i) {
            int ch = chO + wm2 * 128 + i * 16 + quad * 4;
            int hh = ch >> 6, d0 = ch & 63;
            #pragma unroll
            for (int tt = 0; tt < 4; ++tt) {
                int n = tokb + wn4 * 64 + tt * 16 + l15;
                int b = n >> 11, ts = n & 2047;
                ushort4 hv;
                hv.x = f2bf(sentinel(acc[i][tt][0], 1e8f));
                hv.y = f2bf(sentinel(acc[i][tt][1], 1e8f));
                hv.z = f2bf(sentinel(acc[i][tt][2], 1e8f));
                hv.w = f2bf(sentinel(acc[i][tt][3], 1e8f));
                *(ushort4*)&C[((size_t)((b << 4) | hh) * 2048 + wperm(ts)) * 64 + d0] = hv;
            }
        }
    } else {
        // V^T (b,h,d,t'): A row mi holds token tokb+vshufX(mi); r spans 4
        // consecutive t' in world (mi0>>6).
        const int b = tokb >> 11;
        #pragma unroll
        for (int i = 0; i < 8; ++i) {
            int mi0 = wm2 * 128 + i * 16 + quad * 4;
            int colbase = ((mi0 >> 6) << 9) + ((tokb & 2047) >> 2) + (mi0 & 63);
            #pragma unroll
            for (int tt = 0; tt < 4; ++tt) {
                int n = chO + wn4 * 64 + tt * 16 + l15;
                int hh = n >> 6, d = n & 63;
                ushort4 hv;
                hv.x = f2bf(sentinel(acc[i][tt][0], 1e8f));
                hv.y = f2bf(sentinel(acc[i][tt][1], 1e8f));
                hv.z = f2bf(sentinel(acc[i][tt][2], 1e8f));
                hv.w = f2bf(sentinel(acc[i][tt][3], 1e8f));
                *(ushort4*)&C[((size_t)((b << 4) | hh) * 64 + d) * 2048 + colbase] = hv;
            }
        }
    }
}

// ---------------------------------------------------------------------------
// bf16 projection GEMM, swizzled + gld16 (r12/r16-proven 128x64 tile).
// grid (16,32) = 512 blocks (2/CU). XCD-rect swizzle: 8(bx) x 8(by) rect
// per XCD -> per-XCD L2 working set A 2MB + B 1MB.
// ---------------------------------------------------------------------------
__global__ __launch_bounds__(256) void gemm_proj_b(
        const ushort* __restrict__ O, const ushort* __restrict__ wpb,
        float* __restrict__ out)
{
    __shared__ ushort As[128 * 64];
    __shared__ ushort Bs[64 * 64];

    // XCD-rectangle remap (bijective on [0,512))
    const int lin  = blockIdx.x + 16 * blockIdx.y;
    const int xcd  = lin & 7;
    const int slot = lin >> 3;                    // [0,64)
    const int bx   = (xcd & 1) * 8 + (slot % 8);  // [0,16)
    const int by   = (xcd >> 1) * 8 + (slot / 8); // [0,32)

    const int tid  = threadIdx.x;
    const int lane = tid & 63;
    const int wave = tid >> 6;
    const int quad = lane >> 4;
    const int l15  = lane & 15;
    const int bm = by * 128, bn = bx * 64;
    const int wm = (wave & 1) * 64,  wn = (wave >> 1) * 32;

    f32x4 acc[4][2] = {};

    for (int k0 = 0; k0 < 1024; k0 += 64) {
        __syncthreads();
        int h = k0 >> 6;
        #pragma unroll
        for (int j = 0; j < 4; ++j) {
            int cb = j * 256 + wave * 64;
            int ci = cb + lane;
            int r  = ci >> 3;
            int qc = (ci & 7) ^ (r & 7);
            int m = bm + r;
            int b = m >> 11, ts = m & 2047;
            gld16(&O[((((size_t)(b * 16 + h)) * 2048 + wperm(ts)) << 6) + qc * 8],
                  &As[cb * 8]);
        }
        #pragma unroll
        for (int j = 0; j < 2; ++j) {
            int cb = j * 256 + wave * 64;
            int ci = cb + lane;
            int r  = ci >> 3;
            int qc = (ci & 7) ^ (r & 7);
            gld16(&wpb[(size_t)(bn + r) * 1024 + k0 + qc * 8], &Bs[cb * 8]);
        }
        __syncthreads();

        bf16x8 af[2][4], bfr[2][2];
        #pragma unroll
        for (int f = 0; f < 2; ++f) {
            int ch = f * 4 + quad;
            #pragma unroll
            for (int i = 0; i < 4; ++i)
                af[f][i] = *(const bf16x8*)&As[swz(wm + i * 16 + l15, ch)];
            #pragma unroll
            for (int t = 0; t < 2; ++t)
                bfr[f][t] = *(const bf16x8*)&Bs[swz(wn + t * 16 + l15, ch)];
        }
        #pragma unroll
        for (int f = 0; f < 2; ++f)
            #pragma unroll
            for (int i = 0; i < 4; ++i)
                #pragma unroll
                for (int t = 0; t < 2; ++t)
                    acc[i][t] = mfma16(af[f][i], bfr[f][t], acc[i][t]);
    }

    #pragma unroll
    for (int i = 0; i < 4; ++i)
        #pragma unroll
        for (int t = 0; t < 2; ++t)
            #pragma unroll
            for (int r = 0; r < 4; ++r) {
                int m = bm + wm + i * 16 + quad * 4 + r;
                int n = bn + wn + t * 16 + l15;
                out[(size_t)m * 1024 + n] = sentinel(acc[i][t][r], 100.0f);
            }
}

// ---------------------------------------------------------------------------
// Flash attention on WORLD-PERMUTED tokens (block-sparse modal mask).
// S^T orientation, fixed-max exp2 softmax, swizzled LDS, double-buffered K/V
// (1 barrier/iter), lsum via ones-MFMA. 32 q-rows/wave, 4 waves.
// grid (B*H, T/128) = (32,16). In-place Q->O.
// ---------------------------------------------------------------------------
__global__ __launch_bounds__(256) void attn_kernel(
        ushort* __restrict__ Q, const ushort* __restrict__ Kk,
        const ushort* __restrict__ Vt_g, const int* __restrict__ accm)
{
    __shared__ ushort Ks[2][64 * 64];   // k-rows x d, swizzled, dbuf (8KB ea)
    __shared__ ushort Vt[2][64 * 64];   // d-rows x k, swizzled, dbuf
    __shared__ ushort Ps[4][32 * 64];   // per-wave: q-rows x k, swizzled

    const int tid  = threadIdx.x;
    const int lane = tid & 63;
    const int wave = tid >> 6;
    const int quad = lane >> 4;
    const int l15  = lane & 15;
    const int bh = blockIdx.x, qt = blockIdx.y;

    ushort*       Qg = Q    + ((size_t)bh * 2048 + qt * 128) * 64;
    const ushort* Kg = Kk   + (size_t)bh * 2048 * 64;
    const ushort* Vg = Vt_g + (size_t)bh * 64 * 2048;   // (d, t')

    // accessible k-world list for this q-tile's world (diag=1 -> ng >= 1)
    const int qworld = qt >> 2;
    int gpack = 0, ng = 0;
    #pragma unroll
    for (int w = 0; w < 4; ++w)
        if (accm[qworld * 4 + w] != 0) { gpack |= w << (ng * 8); ++ng; }
    const int nkt = ng * 8;
    auto ktof = [&](int i) {
        return ((((gpack >> ((i >> 3) << 3)) & 3) << 3) | (i & 7));
    };

    // Q fragments direct global->VGPR (B-operand: lane l15 = q row)
    bf16x8 aq[2][2];
    #pragma unroll
    for (int i = 0; i < 2; ++i)
        #pragma unroll
        for (int f = 0; f < 2; ++f)
            aq[i][f] = *(const bf16x8*)
                &Qg[(wave * 32 + i * 16 + l15) * 64 + f * 32 + quad * 8];

    bf16x8 aones;
    #pragma unroll
    for (int j = 0; j < 8; ++j) aones[j] = (__bf16)1.0f;

    f32x4 oacc[4][2] = {};  // O^T: [d-tile][q-grp], elem r -> d=dt*16+quad*4+r
    f32x4 lacc[2] = {};     // lsum via ones-MFMA (all rows identical)

    auto stage = [&](int kt, int buf) {
        #pragma unroll
        for (int j = 0; j < 2; ++j) {
            int cb = j * 256 + wave * 64;
            int ci = cb + lane;
            int r  = ci >> 3;
            int qc = (ci & 7) ^ (r & 7);
            gld16(&Kg[((size_t)kt * 64 + r) * 64 + qc * 8], &Ks[buf][cb * 8]);
            gld16(&Vg[(size_t)r * 2048 + kt * 64 + qc * 8], &Vt[buf][cb * 8]);
        }
    };

    stage(ktof(0), 0);
    for (int it = 0; it < nkt; ++it) {
        const int cur = it & 1;
        __syncthreads();                 // drains prefetch of buf[cur]
        if (it < nkt - 1) stage(ktof(it + 1), cur ^ 1);

        // S^T = K Q^T (no mask: whole tile accessible)
        f32x4 st[4][2] = {};
        #pragma unroll
        for (int f = 0; f < 2; ++f) {
            int ch = f * 4 + quad;
            #pragma unroll
            for (int k4 = 0; k4 < 4; ++k4) {
                bf16x8 ak = *(const bf16x8*)&Ks[cur][swz(k4 * 16 + l15, ch)];
                #pragma unroll
                for (int i = 0; i < 2; ++i)
                    st[k4][i] = mfma16(ak, aq[i][f], st[k4][i]);
            }
        }

        // P = exp2(S^T) -> packed b64 writes into per-wave Ps strip
        #pragma unroll
        for (int i = 0; i < 2; ++i) {
            int prow = i * 16 + l15;
            #pragma unroll
            for (int k4 = 0; k4 < 4; ++k4) {
                float p0 = fexp2(st[k4][i][0]);
                float p1 = fexp2(st[k4][i][1]);
                float p2 = fexp2(st[k4][i][2]);
                float p3 = fexp2(st[k4][i][3]);
                ushort2 lo = pk2(p0, p1), hi = pk2(p2, p3);
                ushort4 pv4; pv4.x = lo.x; pv4.y = lo.y;
                pv4.z = hi.x; pv4.w = hi.y;
                int pc8 = (k4 * 2 + (quad >> 1)) ^ (l15 & 7);
                *(ushort4*)&Ps[wave][prow * 64 + pc8 * 8 + (quad & 1) * 4] = pv4;
            }
        }

        // O^T += Vt P^T ; lsum += ones . P^T  (within-wave LDS ordering)
        bf16x8 bp[2][2];
        #pragma unroll
        for (int i = 0; i < 2; ++i)
            #pragma unroll
            for (int f = 0; f < 2; ++f)
                bp[i][f] = *(const bf16x8*)&Ps[wave][swz(i * 16 + l15, f * 4 + quad)];
        #pragma unroll
        for (int f = 0; f < 2; ++f) {
            int ch = f * 4 + quad;
            #pragma unroll
            for (int i = 0; i < 2; ++i)
                lacc[i] = mfma16(aones, bp[i][f], lacc[i]);
            #pragma unroll
            for (int dt = 0; dt < 4; ++dt) {
                bf16x8 av = *(const bf16x8*)&Vt[cur][swz(dt * 16 + l15, ch)];
                #pragma unroll
                for (int i = 0; i < 2; ++i)
                    oacc[dt][i] = mfma16(av, bp[i][f], oacc[dt][i]);
            }
        }
    }

    // lacc rows all equal total lsum for q = wave*32+i*16+l15
    #pragma unroll
    for (int i = 0; i < 2; ++i) {
        const float inv = 1.0f / lacc[i][0];
        #pragma unroll
        for (int dt = 0; dt < 4; ++dt) {
            ushort4 o4;
            o4.x = f2bf(sentinel(oacc[dt][i][0] * inv, 1e4f));
            o4.y = f2bf(sentinel(oacc[dt][i][1] * inv, 1e4f));
            o4.z = f2bf(sentinel(oacc[dt][i][2] * inv, 1e4f));
            o4.w = f2bf(sentinel(oacc[dt][i][3] * inv, 1e4f));
            *(ushort4*)&Qg[(wave * 32 + i * 16 + l15) * 64 + dt * 16 + quad * 4] = o4;
        }
    }
}

// ---------------------------------------------------------------------------
// FALLBACK (ws < 40MB): fp32-staging GEMMs (proven in r8/r9), world-permuted
// layouts + vshuf'd V^T epilogue (r16 form; correct, not perf-critical).
// ---------------------------------------------------------------------------
__global__ __launch_bounds__(256) void gemm_qkv_f32(
        const float* __restrict__ A,
        const float* __restrict__ Wq, const float* __restrict__ Wk,
        const float* __restrict__ Wv,
        ushort* __restrict__ Cq, ushort* __restrict__ Ck,
        ushort* __restrict__ Cv)
{
    __shared__ __align__(16) ushort As[128 * 72];
    __shared__ __align__(16) ushort Bs[128 * 72];

    const int sel = blockIdx.x >> 3;
    const float* __restrict__ Bw = sel == 0 ? Wq : (sel == 1 ? Wk : Wv);
    ushort* __restrict__ C       = sel == 0 ? Cq : (sel == 1 ? Ck : Cv);
    const float scale = sel == 0 ? QSCALE : 1.0f;

    const int tid  = threadIdx.x;
    const int lane = tid & 63;
    const int wave = tid >> 6;
    const int quad = lane >> 4;
    const int l15  = lane & 15;
    const int bm = blockIdx.y * 128;
    const int bn = (blockIdx.x & 7) * 128;
    const int wm = (wave & 1) * 64, wn = (wave >> 1) * 64;

    f32x4 acc[4][4] = {};

    for (int k0 = 0; k0 < 1024; k0 += 64) {
        __syncthreads();
        #pragma unroll
        for (int i = 0; i < 8; ++i) {
            int c = tid + 256 * i;
            int row = c >> 4, col = (c & 15) * 4;
            int rg = (sel == 2) ? vshuf(row) : row;
            float4 a4 = *(const float4*)&A[(size_t)(bm + rg) * 1024 + k0 + col];
            *(ushort4*)&As[row * 72 + col] = cvt4(a4);
            float4 b4 = *(const float4*)&Bw[(size_t)(bn + row) * 1024 + k0 + col];
            *(ushort4*)&Bs[row * 72 + col] = cvt4s(b4, scale);
        }
        __syncthreads();

        bf16x8 af[2][4], bfr[2][4];
        #pragma unroll
        for (int f = 0; f < 2; ++f)
            #pragma unroll
            for (int i = 0; i < 4; ++i) {
                af[f][i]  = *(const bf16x8*)&As[(wm + i * 16 + l15) * 72 + f * 32 + quad * 8];
                bfr[f][i] = *(const bf16x8*)&Bs[(wn + i * 16 + l15) * 72 + f * 32 + quad * 8];
            }
        #pragma unroll
        for (int f = 0; f < 2; ++f)
            #pragma unroll
            for (int i = 0; i < 4; ++i)
                #pragma unroll
                for (int t = 0; t < 4; ++t)
                    acc[i][t] = mfma16(af[f][i], bfr[f][t], acc[i][t]);
    }

    if (sel < 2) {
        #pragma unroll
        for (int i = 0; i < 4; ++i)
            #pragma unroll
            for (int t = 0; t < 4; ++t)
                #pragma unroll
                for (int r = 0; r < 4; ++r) {
                    int m = bm + wm + i * 16 + quad * 4 + r;
                    int n = bn + wn + t * 16 + l15;
                    int b = m >> 11, ts = m & 2047, hh = n >> 6, d = n & 63;
                    C[((size_t)((b << 4) | hh) * 2048 + wperm(ts)) * 64 + d] =
                        f2bf(sentinel(acc[i][t][r], 1e8f));
                }
    } else {
        const int b = bm >> 11;
        #pragma unroll
        for (int i = 0; i < 4; ++i) {
            int mi0 = wm + i * 16 + quad * 4;
            int colbase = ((mi0 >> 5) << 9) + ((bm & 2047) >> 2) + (mi0 & 31);
            #pragma unroll
            for (int t = 0; t < 4; ++t) {
                int n = bn + wn + t * 16 + l15;
                int hh = n >> 6, d = n & 63;
                ushort4 hv;
                hv.x = f2bf(sentinel(acc[i][t][0], 1e8f));
                hv.y = f2bf(sentinel(acc[i][t][1], 1e8f));
                hv.z = f2bf(sentinel(acc[i][t][2], 1e8f));
                hv.w = f2bf(sentinel(acc[i][t][3], 1e8f));
                *(ushort4*)&C[((size_t)((b << 4) | hh) * 64 + d) * 2048 + colbase] = hv;
            }
        }
    }
}

__global__ __launch_bounds__(256) void gemm_proj_f32(
        const ushort* __restrict__ A, const float* __restrict__ Bw,
        float* __restrict__ C)
{
    __shared__ __align__(16) ushort As[128 * 72];
    __shared__ __align__(16) ushort Bs[64 * 72];

    const int tid  = threadIdx.x;
    const int lane = tid & 63;
    const int wave = tid >> 6;
    const int quad = lane >> 4;
    const int l15  = lane & 15;
    const int bm = blockIdx.y * 128, bn = blockIdx.x * 64;
    const int wm = (wave & 1) * 64,  wn = (wave >> 1) * 32;

    f32x4 acc[4][2] = {};

    for (int k0 = 0; k0 < 1024; k0 += 64) {
        __syncthreads();
        #pragma unroll
        for (int i = 0; i < 4; ++i) {
            int c = tid + 256 * i;
            int row = c >> 3, col = (c & 7) * 8;
            int m = bm + row;
            int b = m >> 11, ts = m & 2047, h = k0 >> 6;
            size_t aoff = ((((size_t)(b * 16 + h)) * 2048 + wperm(ts)) << 6) + col;
            *(ushort8*)&As[row * 72 + col] = *(const ushort8*)&A[aoff];
        }
        #pragma unroll
        for (int i = 0; i < 4; ++i) {
            int c = tid + 256 * i;
            int row = c >> 4, col = (c & 15) * 4;
            float4 b4 = *(const float4*)&Bw[(size_t)(bn + row) * 1024 + k0 + col];
            *(ushort4*)&Bs[row * 72 + col] = cvt4(b4);
        }
        __syncthreads();

        bf16x8 af[2][4], bfr[2][2];
        #pragma unroll
        for (int f = 0; f < 2; ++f) {
            #pragma unroll
            for (int i = 0; i < 4; ++i)
                af[f][i] = *(const bf16x8*)&As[(wm + i * 16 + l15) * 72 + f * 32 + quad * 8];
            #pragma unroll
            for (int t = 0; t < 2; ++t)
                bfr[f][t] = *(const bf16x8*)&Bs[(wn + t * 16 + l15) * 72 + f * 32 + quad * 8];
        }
        #pragma unroll
        for (int f = 0; f < 2; ++f)
            #pragma unroll
            for (int i = 0; i < 4; ++i)
                #pragma unroll
                for (int t = 0; t < 2; ++t)
                    acc[i][t] = mfma16(af[f][i], bfr[f][t], acc[i][t]);
    }

    #pragma unroll
    for (int i = 0; i < 4; ++i)
        #pragma unroll
        for (int t = 0; t < 2; ++t)
            #pragma unroll
            for (int r = 0; r < 4; ++r) {
                int m = bm + wm + i * 16 + quad * 4 + r;
                int n = bn + wn + t * 16 + l15;
                C[(size_t)m * 1024 + n] = sentinel(acc[i][t][r], 100.0f);
            }
}

// ---------------------------------------------------------------------------
__global__ void diag_kernel(float* out, int n, float val) {
    int i = blockIdx.x * blockDim.x + threadIdx.x;
    if (i < n) out[i] = (i == 0) ? val : 0.f;
}

// ---------------------------------------------------------------------------
extern "C" void kernel_launch(void* const* d_in, const int* in_sizes, int n_in,
                              void* d_out, int out_size, void* d_ws, size_t ws_size,
                              hipStream_t stream) {
    const float* x  = (const float*)d_in[0];
    const float* Wq = (const float*)d_in[1];
    const float* Wk = (const float*)d_in[2];
    const float* Wv = (const float*)d_in[3];
    const float* Wp = (const float*)d_in[4];
    const int* accm = (const int*)d_in[5];
    float* out = (float*)d_out;

    const size_t SZ = (size_t)4 * 1024 * 1024;
    const size_t WSZ = (size_t)1024 * 1024;

    if (ws_size < 3 * SZ * sizeof(ushort)) {
        diag_kernel<<<(out_size + 255) / 256, 256, 0, stream>>>(
            out, out_size, (float)ws_size);
        return;
    }

    ushort* k_ws = (ushort*)d_ws;          // (b,h,t',d) world-permuted
    ushort* v_ws = k_ws + SZ;              // (b,h,d,t') TRANSPOSED, permuted
    ushort* q_ws = v_ws + SZ;              // (b,h,t',d), pre-scaled, permuted
    dim3 blk(256);

    const size_t need_fast = (4 * SZ + 4 * WSZ) * sizeof(ushort); // 40 MB
    if (ws_size >= need_fast) {
        ushort* xb  = q_ws + SZ;
        ushort* wqb = xb + SZ;
        ushort* wkb = wqb + WSZ;
        ushort* wvb = wkb + WSZ;
        ushort* wpb = wvb + WSZ;
        cvt_prepass<<<8192, blk, 0, stream>>>(x, Wq, Wk, Wv, Wp,
                                              xb, wqb, wkb, wvb, wpb);
        gemm_qkv_b<<<dim3(192), dim3(512), 0, stream>>>(xb, wqb, wkb, wvb,
                                                        q_ws, k_ws, v_ws);
        attn_kernel<<<dim3(32, 16), blk, 0, stream>>>(q_ws, k_ws, v_ws, accm);
        gemm_proj_b<<<dim3(16, 32), blk, 0, stream>>>(q_ws, wpb, out);
    } else {
        gemm_qkv_f32<<<dim3(24, 32), blk, 0, stream>>>(x, Wq, Wk, Wv,
                                                       q_ws, k_ws, v_ws);
        attn_kernel<<<dim3(32, 16), blk, 0, stream>>>(q_ws, k_ws, v_ws, accm);
        gemm_proj_f32<<<dim3(16, 32), blk, 0, stream>>>(q_ws, Wp, out);
    }
}

// Round 9
// 155.384 us; speedup vs baseline: 1.0531x; 1.0531x over previous
//
#include <hip/hip_runtime.h>
#include <hip/hip_bf16.h>
#include <stdint.h>

// ModalAttention: B=2, T=2048, C=1024, H=16, D=64, N_WORLDS=4
// ESTABLISHED: inputs fp32, accessibility int32, OUTPUT fp32, ws >= 40 MB.
// Round 21: REVERT qkv to r19 (r20's 256^2/BK=32 was neutral on qkv, worse
//  total: bank conflicts 0->2.4M, FETCH 20.5->43MB, 1 block/CU). Apply the
//  r19-proven OPERAND SWAP to gemm_proj_b: A=Wp channel-rows, B=O token-rows
//  -> 4 consecutive out-channels in reg idx -> 8 aligned float4 stores
//  (was 32 scalar 4B). Same dot products, same k-order -> bit-identical.
//  qkv/attn/cvt/fallback = r19 exact.

typedef __attribute__((ext_vector_type(8))) __bf16   bf16x8;
typedef __attribute__((ext_vector_type(4))) float    f32x4;
typedef __attribute__((ext_vector_type(8))) ushort   ushort8;

__device__ __forceinline__ ushort f2bf(float x) {
    uint32_t u = __float_as_uint(x);
    return (ushort)((u + 0x7fffu + ((u >> 16) & 1u)) >> 16);
}
__device__ __forceinline__ float sentinel(float v, float s) {
    return (fabsf(v) < 1e30f) ? v : s;
}
__device__ __forceinline__ f32x4 mfma16(bf16x8 a, bf16x8 b, f32x4 c) {
    return __builtin_amdgcn_mfma_f32_16x16x32_bf16(a, b, c, 0, 0, 0);
}
__device__ __forceinline__ ushort2 pk2(float a, float b) {
    __hip_bfloat162 h = __float22bfloat162_rn(make_float2(a, b));
    union { __hip_bfloat162 h; ushort2 u; } c; c.h = h; return c.u;
}
__device__ __forceinline__ ushort4 cvt4(float4 v) {
    ushort2 lo = pk2(v.x, v.y), hi = pk2(v.z, v.w);
    ushort4 r; r.x = lo.x; r.y = lo.y; r.z = hi.x; r.w = hi.y; return r;
}
__device__ __forceinline__ ushort4 cvt4s(float4 v, float s) {
    ushort2 lo = pk2(v.x * s, v.y * s), hi = pk2(v.z * s, v.w * s);
    ushort4 r; r.x = lo.x; r.y = lo.y; r.z = hi.x; r.w = hi.y; return r;
}
__device__ __forceinline__ float fexp2(float x) {
#if __has_builtin(__builtin_amdgcn_exp2f)
    return __builtin_amdgcn_exp2f(x);
#else
    return exp2f(x);
#endif
}
__device__ __forceinline__ void gld16(const ushort* g, ushort* l) {
    auto* g1 = reinterpret_cast<const __attribute__((address_space(1))) uint32_t*>(
        reinterpret_cast<uintptr_t>(g));
    auto* l3 = reinterpret_cast<__attribute__((address_space(3))) uint32_t*>(
        reinterpret_cast<uintptr_t>(l));
    __builtin_amdgcn_global_load_lds(g1, l3, 16, 0, 0);
}

// swizzled element-offset of 8-elem chunk `ch` in row `row` of a 64-col tile
__device__ __forceinline__ int swz(int row, int ch) {
    return row * 64 + ((ch ^ (row & 7)) * 8);
}

// world-permuted token index: t -> (t%4)*512 + t/4
__device__ __forceinline__ int wperm(int ts) {
    return ((ts & 3) << 9) | (ts >> 2);
}

// V A-tile row shuffle: tile row r holds global row tokb + vshuf(r).
// vshuf(r) = 4*(r&31) + (r>>5); bijection on [0,128).
__device__ __forceinline__ int vshuf(int r) {
    return ((r & 31) << 2) | (r >> 5);
}

#define QSCALE 0.1803368801111244f   // 1/sqrt(64) * log2(e)

// ---------------------------------------------------------------------------
// Prepass: fp32 -> bf16 (x, Wq*QSCALE, Wk, Wv, Wp).
// ---------------------------------------------------------------------------
__global__ __launch_bounds__(256) void cvt_prepass(
        const float* __restrict__ x,  const float* __restrict__ Wq,
        const float* __restrict__ Wk, const float* __restrict__ Wv,
        const float* __restrict__ Wp,
        ushort* __restrict__ xb,  ushort* __restrict__ wqb,
        ushort* __restrict__ wkb, ushort* __restrict__ wvb,
        ushort* __restrict__ wpb)
{
    int gid = blockIdx.x;
    const float* src; ushort* dst; float sc = 1.0f; int boff;
    if (gid < 4096)      { src = x;  dst = xb;  boff = gid; }
    else if (gid < 5120) { src = Wq; dst = wqb; boff = gid - 4096; sc = QSCALE; }
    else if (gid < 6144) { src = Wk; dst = wkb; boff = gid - 5120; }
    else if (gid < 7168) { src = Wv; dst = wvb; boff = gid - 6144; }
    else                 { src = Wp; dst = wpb; boff = gid - 7168; }
    size_t idx = (size_t)boff * 1024 + threadIdx.x * 4;
    float4 v = *(const float4*)&src[idx];
    *(ushort4*)&dst[idx] = cvt4s(v, sc);
}

// ---------------------------------------------------------------------------
// bf16 fused QKV GEMM, swizzled LDS + gld16, XCD-rect swizzle (r18/r19).
// sel<2 (Q,K): A = W channel-rows, B = x token-rows -> D row dim = 4
//   consecutive d within a head -> ushort4 epilogue into (b,h,t',d).
// sel==2 (V): A = x token-rows vshuf'd, B = Wv -> ushort4 into (b,h,d,t').
// ---------------------------------------------------------------------------
__global__ __launch_bounds__(256) void gemm_qkv_b(
        const ushort* __restrict__ xb,
        const ushort* __restrict__ wqb, const ushort* __restrict__ wkb,
        const ushort* __restrict__ wvb,
        ushort* __restrict__ Cq, ushort* __restrict__ Ck,
        ushort* __restrict__ Cv)
{
    __shared__ ushort As[128 * 64];
    __shared__ ushort Bs[128 * 64];

    // XCD-rectangle remap (bijective on [0,768)): hw round-robin lin%8 = XCD
    const int lin  = blockIdx.x + 24 * blockIdx.y;
    const int xcd  = lin & 7;
    const int slot = lin >> 3;                    // [0,96)
    const int bx   = (xcd & 1) * 12 + (slot % 12); // [0,24)
    const int by   = (xcd >> 1) * 8 + (slot / 12); // [0,32)

    const int sel = bx >> 3;
    const ushort* __restrict__ Bw = sel == 0 ? wqb : (sel == 1 ? wkb : wvb);
    ushort* __restrict__ C        = sel == 0 ? Cq : (sel == 1 ? Ck : Cv);

    const int tid  = threadIdx.x;
    const int lane = tid & 63;
    const int wave = tid >> 6;
    const int quad = lane >> 4;
    const int l15  = lane & 15;
    const int tokb = by * 128;          // token block (B*T dim)
    const int chb  = (bx & 7) * 128;    // output-channel block (C dim)
    const int wm = (wave & 1) * 64, wn = (wave >> 1) * 64;

    f32x4 acc[4][4] = {};

    for (int k0 = 0; k0 < 1024; k0 += 64) {
        __syncthreads();
        #pragma unroll
        for (int j = 0; j < 4; ++j) {
            int cb = j * 256 + wave * 64;
            int ci = cb + lane;
            int r  = ci >> 3;
            int qc = (ci & 7) ^ (r & 7);
            if (sel < 2) {
                gld16(&Bw[(size_t)(chb + r) * 1024 + k0 + qc * 8], &As[cb * 8]);
                gld16(&xb[(size_t)(tokb + r) * 1024 + k0 + qc * 8], &Bs[cb * 8]);
            } else {
                gld16(&xb[(size_t)(tokb + vshuf(r)) * 1024 + k0 + qc * 8], &As[cb * 8]);
                gld16(&Bw[(size_t)(chb + r) * 1024 + k0 + qc * 8], &Bs[cb * 8]);
            }
        }
        __syncthreads();

        bf16x8 af[2][4], bfr[2][4];
        #pragma unroll
        for (int f = 0; f < 2; ++f)
            #pragma unroll
            for (int i = 0; i < 4; ++i) {
                int ch = f * 4 + quad;
                af[f][i]  = *(const bf16x8*)&As[swz(wm + i * 16 + l15, ch)];
                bfr[f][i] = *(const bf16x8*)&Bs[swz(wn + i * 16 + l15, ch)];
            }
        #pragma unroll
        for (int f = 0; f < 2; ++f)
            #pragma unroll
            for (int i = 0; i < 4; ++i)
                #pragma unroll
                for (int t = 0; t < 4; ++t)
                    acc[i][t] = mfma16(af[f][i], bfr[f][t], acc[i][t]);
    }

    if (sel < 2) {
        // Q/K -> (b,h,t',d): D row = channel (r spans 4 consecutive d).
        #pragma unroll
        for (int i = 0; i < 4; ++i) {
            int ch = chb + wm + i * 16 + quad * 4;
            int hh = ch >> 6, d0 = ch & 63;
            #pragma unroll
            for (int t = 0; t < 4; ++t) {
                int n = tokb + wn + t * 16 + l15;
                int b = n >> 11, ts = n & 2047;
                ushort4 hv;
                hv.x = f2bf(sentinel(acc[i][t][0], 1e8f));
                hv.y = f2bf(sentinel(acc[i][t][1], 1e8f));
                hv.z = f2bf(sentinel(acc[i][t][2], 1e8f));
                hv.w = f2bf(sentinel(acc[i][t][3], 1e8f));
                *(ushort4*)&C[((size_t)((b << 4) | hh) * 2048 + wperm(ts)) * 64 + d0] = hv;
            }
        }
    } else {
        // V^T (b,h,d,t'). Tile row mi holds global ts = tokb + vshuf(mi), so
        // r=0..3 -> 4 consecutive t' in world (mi>>5). One ushort4 per (i,t):
        // col = (mi0>>5)*512 + ((tokb&2047)>>2) + (mi0&31).
        const int b = tokb >> 11;
        #pragma unroll
        for (int i = 0; i < 4; ++i) {
            int mi0 = wm + i * 16 + quad * 4;
            int colbase = ((mi0 >> 5) << 9) + ((tokb & 2047) >> 2) + (mi0 & 31);
            #pragma unroll
            for (int t = 0; t < 4; ++t) {
                int n = chb + wn + t * 16 + l15;
                int hh = n >> 6, d = n & 63;
                ushort4 hv;
                hv.x = f2bf(sentinel(acc[i][t][0], 1e8f));
                hv.y = f2bf(sentinel(acc[i][t][1], 1e8f));
                hv.z = f2bf(sentinel(acc[i][t][2], 1e8f));
                hv.w = f2bf(sentinel(acc[i][t][3], 1e8f));
                *(ushort4*)&C[((size_t)((b << 4) | hh) * 64 + d) * 2048 + colbase] = hv;
            }
        }
    }
}

// ---------------------------------------------------------------------------
// bf16 projection GEMM with OPERAND SWAP: A = Wp channel-rows (64/tile),
// B = O token-rows (128/tile, wperm gather). D row dim = 4 consecutive out
// channels -> float4 epilogue. grid (16,32) = 512 blocks (2/CU), XCD-rect.
// ---------------------------------------------------------------------------
__global__ __launch_bounds__(256) void gemm_proj_b(
        const ushort* __restrict__ O, const ushort* __restrict__ wpb,
        float* __restrict__ out)
{
    __shared__ ushort As[64 * 64];    // Wp: 64 out-channels x 64 k
    __shared__ ushort Bs[128 * 64];   // O: 128 tokens x 64 k

    // XCD-rectangle remap (bijective on [0,512))
    const int lin  = blockIdx.x + 16 * blockIdx.y;
    const int xcd  = lin & 7;
    const int slot = lin >> 3;                    // [0,64)
    const int bx   = (xcd & 1) * 8 + (slot % 8);  // ch tile [0,16)
    const int by   = (xcd >> 1) * 8 + (slot / 8); // tok tile [0,32)

    const int tid  = threadIdx.x;
    const int lane = tid & 63;
    const int wave = tid >> 6;
    const int quad = lane >> 4;
    const int l15  = lane & 15;
    const int chb = bx * 64, tokb = by * 128;
    const int wm = (wave & 1) * 32,  wn = (wave >> 1) * 64;

    f32x4 acc[2][4] = {};

    for (int k0 = 0; k0 < 1024; k0 += 64) {
        __syncthreads();
        int h = k0 >> 6;
        #pragma unroll
        for (int j = 0; j < 2; ++j) {
            int cb = j * 256 + wave * 64;
            int ci = cb + lane;
            int r  = ci >> 3;
            int qc = (ci & 7) ^ (r & 7);
            gld16(&wpb[(size_t)(chb + r) * 1024 + k0 + qc * 8], &As[cb * 8]);
        }
        #pragma unroll
        for (int j = 0; j < 4; ++j) {
            int cb = j * 256 + wave * 64;
            int ci = cb + lane;
            int r  = ci >> 3;
            int qc = (ci & 7) ^ (r & 7);
            int m = tokb + r;
            int b = m >> 11, ts = m & 2047;
            gld16(&O[((((size_t)(b * 16 + h)) * 2048 + wperm(ts)) << 6) + qc * 8],
                  &Bs[cb * 8]);
        }
        __syncthreads();

        bf16x8 af[2][2], bfr[2][4];
        #pragma unroll
        for (int f = 0; f < 2; ++f) {
            int ch = f * 4 + quad;
            #pragma unroll
            for (int i = 0; i < 2; ++i)
                af[f][i] = *(const bf16x8*)&As[swz(wm + i * 16 + l15, ch)];
            #pragma unroll
            for (int t = 0; t < 4; ++t)
                bfr[f][t] = *(const bf16x8*)&Bs[swz(wn + t * 16 + l15, ch)];
        }
        #pragma unroll
        for (int f = 0; f < 2; ++f)
            #pragma unroll
            for (int i = 0; i < 2; ++i)
                #pragma unroll
                for (int t = 0; t < 4; ++t)
                    acc[i][t] = mfma16(af[f][i], bfr[f][t], acc[i][t]);
    }

    // out[token][ch]: r spans 4 consecutive out channels -> float4.
    #pragma unroll
    for (int i = 0; i < 2; ++i) {
        int n0 = chb + wm + i * 16 + quad * 4;
        #pragma unroll
        for (int t = 0; t < 4; ++t) {
            int m = tokb + wn + t * 16 + l15;
            float4 v4;
            v4.x = sentinel(acc[i][t][0], 100.0f);
            v4.y = sentinel(acc[i][t][1], 100.0f);
            v4.z = sentinel(acc[i][t][2], 100.0f);
            v4.w = sentinel(acc[i][t][3], 100.0f);
            *(float4*)&out[(size_t)m * 1024 + n0] = v4;
        }
    }
}

// ---------------------------------------------------------------------------
// Flash attention on WORLD-PERMUTED tokens (block-sparse modal mask).
// S^T orientation, fixed-max exp2 softmax, swizzled LDS, double-buffered K/V
// (1 barrier/iter), lsum via ones-MFMA. 32 q-rows/wave, 4 waves.
// grid (B*H, T/128) = (32,16). In-place Q->O.
// ---------------------------------------------------------------------------
__global__ __launch_bounds__(256) void attn_kernel(
        ushort* __restrict__ Q, const ushort* __restrict__ Kk,
        const ushort* __restrict__ Vt_g, const int* __restrict__ accm)
{
    __shared__ ushort Ks[2][64 * 64];   // k-rows x d, swizzled, dbuf (8KB ea)
    __shared__ ushort Vt[2][64 * 64];   // d-rows x k, swizzled, dbuf
    __shared__ ushort Ps[4][32 * 64];   // per-wave: q-rows x k, swizzled

    const int tid  = threadIdx.x;
    const int lane = tid & 63;
    const int wave = tid >> 6;
    const int quad = lane >> 4;
    const int l15  = lane & 15;
    const int bh = blockIdx.x, qt = blockIdx.y;

    ushort*       Qg = Q    + ((size_t)bh * 2048 + qt * 128) * 64;
    const ushort* Kg = Kk   + (size_t)bh * 2048 * 64;
    const ushort* Vg = Vt_g + (size_t)bh * 64 * 2048;   // (d, t')

    // accessible k-world list for this q-tile's world (diag=1 -> ng >= 1)
    const int qworld = qt >> 2;
    int gpack = 0, ng = 0;
    #pragma unroll
    for (int w = 0; w < 4; ++w)
        if (accm[qworld * 4 + w] != 0) { gpack |= w << (ng * 8); ++ng; }
    const int nkt = ng * 8;
    auto ktof = [&](int i) {
        return ((((gpack >> ((i >> 3) << 3)) & 3) << 3) | (i & 7));
    };

    // Q fragments direct global->VGPR (B-operand: lane l15 = q row)
    bf16x8 aq[2][2];
    #pragma unroll
    for (int i = 0; i < 2; ++i)
        #pragma unroll
        for (int f = 0; f < 2; ++f)
            aq[i][f] = *(const bf16x8*)
                &Qg[(wave * 32 + i * 16 + l15) * 64 + f * 32 + quad * 8];

    bf16x8 aones;
    #pragma unroll
    for (int j = 0; j < 8; ++j) aones[j] = (__bf16)1.0f;

    f32x4 oacc[4][2] = {};  // O^T: [d-tile][q-grp], elem r -> d=dt*16+quad*4+r
    f32x4 lacc[2] = {};     // lsum via ones-MFMA (all rows identical)

    auto stage = [&](int kt, int buf) {
        #pragma unroll
        for (int j = 0; j < 2; ++j) {
            int cb = j * 256 + wave * 64;
            int ci = cb + lane;
            int r  = ci >> 3;
            int qc = (ci & 7) ^ (r & 7);
            gld16(&Kg[((size_t)kt * 64 + r) * 64 + qc * 8], &Ks[buf][cb * 8]);
            gld16(&Vg[(size_t)r * 2048 + kt * 64 + qc * 8], &Vt[buf][cb * 8]);
        }
    };

    stage(ktof(0), 0);
    for (int it = 0; it < nkt; ++it) {
        const int cur = it & 1;
        __syncthreads();                 // drains prefetch of buf[cur]
        if (it < nkt - 1) stage(ktof(it + 1), cur ^ 1);

        // S^T = K Q^T (no mask: whole tile accessible)
        f32x4 st[4][2] = {};
        #pragma unroll
        for (int f = 0; f < 2; ++f) {
            int ch = f * 4 + quad;
            #pragma unroll
            for (int k4 = 0; k4 < 4; ++k4) {
                bf16x8 ak = *(const bf16x8*)&Ks[cur][swz(k4 * 16 + l15, ch)];
                #pragma unroll
                for (int i = 0; i < 2; ++i)
                    st[k4][i] = mfma16(ak, aq[i][f], st[k4][i]);
            }
        }

        // P = exp2(S^T) -> packed b64 writes into per-wave Ps strip
        #pragma unroll
        for (int i = 0; i < 2; ++i) {
            int prow = i * 16 + l15;
            #pragma unroll
            for (int k4 = 0; k4 < 4; ++k4) {
                float p0 = fexp2(st[k4][i][0]);
                float p1 = fexp2(st[k4][i][1]);
                float p2 = fexp2(st[k4][i][2]);
                float p3 = fexp2(st[k4][i][3]);
                ushort2 lo = pk2(p0, p1), hi = pk2(p2, p3);
                ushort4 pv4; pv4.x = lo.x; pv4.y = lo.y;
                pv4.z = hi.x; pv4.w = hi.y;
                int pc8 = (k4 * 2 + (quad >> 1)) ^ (l15 & 7);
                *(ushort4*)&Ps[wave][prow * 64 + pc8 * 8 + (quad & 1) * 4] = pv4;
            }
        }

        // O^T += Vt P^T ; lsum += ones . P^T  (within-wave LDS ordering)
        bf16x8 bp[2][2];
        #pragma unroll
        for (int i = 0; i < 2; ++i)
            #pragma unroll
            for (int f = 0; f < 2; ++f)
                bp[i][f] = *(const bf16x8*)&Ps[wave][swz(i * 16 + l15, f * 4 + quad)];
        #pragma unroll
        for (int f = 0; f < 2; ++f) {
            int ch = f * 4 + quad;
            #pragma unroll
            for (int i = 0; i < 2; ++i)
                lacc[i] = mfma16(aones, bp[i][f], lacc[i]);
            #pragma unroll
            for (int dt = 0; dt < 4; ++dt) {
                bf16x8 av = *(const bf16x8*)&Vt[cur][swz(dt * 16 + l15, ch)];
                #pragma unroll
                for (int i = 0; i < 2; ++i)
                    oacc[dt][i] = mfma16(av, bp[i][f], oacc[dt][i]);
            }
        }
    }

    // lacc rows all equal total lsum for q = wave*32+i*16+l15
    #pragma unroll
    for (int i = 0; i < 2; ++i) {
        const float inv = 1.0f / lacc[i][0];
        #pragma unroll
        for (int dt = 0; dt < 4; ++dt) {
            ushort4 o4;
            o4.x = f2bf(sentinel(oacc[dt][i][0] * inv, 1e4f));
            o4.y = f2bf(sentinel(oacc[dt][i][1] * inv, 1e4f));
            o4.z = f2bf(sentinel(oacc[dt][i][2] * inv, 1e4f));
            o4.w = f2bf(sentinel(oacc[dt][i][3] * inv, 1e4f));
            *(ushort4*)&Qg[(wave * 32 + i * 16 + l15) * 64 + dt * 16 + quad * 4] = o4;
        }
    }
}

// ---------------------------------------------------------------------------
// FALLBACK (ws < 40MB): fp32-staging GEMMs (proven in r8/r9), world-permuted
// layouts + vshuf'd V^T epilogue (r16 form; correct, not perf-critical).
// ---------------------------------------------------------------------------
__global__ __launch_bounds__(256) void gemm_qkv_f32(
        const float* __restrict__ A,
        const float* __restrict__ Wq, const float* __restrict__ Wk,
        const float* __restrict__ Wv,
        ushort* __restrict__ Cq, ushort* __restrict__ Ck,
        ushort* __restrict__ Cv)
{
    __shared__ __align__(16) ushort As[128 * 72];
    __shared__ __align__(16) ushort Bs[128 * 72];

    const int sel = blockIdx.x >> 3;
    const float* __restrict__ Bw = sel == 0 ? Wq : (sel == 1 ? Wk : Wv);
    ushort* __restrict__ C       = sel == 0 ? Cq : (sel == 1 ? Ck : Cv);
    const float scale = sel == 0 ? QSCALE : 1.0f;

    const int tid  = threadIdx.x;
    const int lane = tid & 63;
    const int wave = tid >> 6;
    const int quad = lane >> 4;
    const int l15  = lane & 15;
    const int bm = blockIdx.y * 128;
    const int bn = (blockIdx.x & 7) * 128;
    const int wm = (wave & 1) * 64, wn = (wave >> 1) * 64;

    f32x4 acc[4][4] = {};

    for (int k0 = 0; k0 < 1024; k0 += 64) {
        __syncthreads();
        #pragma unroll
        for (int i = 0; i < 8; ++i) {
            int c = tid + 256 * i;
            int row = c >> 4, col = (c & 15) * 4;
            int rg = (sel == 2) ? vshuf(row) : row;
            float4 a4 = *(const float4*)&A[(size_t)(bm + rg) * 1024 + k0 + col];
            *(ushort4*)&As[row * 72 + col] = cvt4(a4);
            float4 b4 = *(const float4*)&Bw[(size_t)(bn + row) * 1024 + k0 + col];
            *(ushort4*)&Bs[row * 72 + col] = cvt4s(b4, scale);
        }
        __syncthreads();

        bf16x8 af[2][4], bfr[2][4];
        #pragma unroll
        for (int f = 0; f < 2; ++f)
            #pragma unroll
            for (int i = 0; i < 4; ++i) {
                af[f][i]  = *(const bf16x8*)&As[(wm + i * 16 + l15) * 72 + f * 32 + quad * 8];
                bfr[f][i] = *(const bf16x8*)&Bs[(wn + i * 16 + l15) * 72 + f * 32 + quad * 8];
            }
        #pragma unroll
        for (int f = 0; f < 2; ++f)
            #pragma unroll
            for (int i = 0; i < 4; ++i)
                #pragma unroll
                for (int t = 0; t < 4; ++t)
                    acc[i][t] = mfma16(af[f][i], bfr[f][t], acc[i][t]);
    }

    if (sel < 2) {
        #pragma unroll
        for (int i = 0; i < 4; ++i)
            #pragma unroll
            for (int t = 0; t < 4; ++t)
                #pragma unroll
                for (int r = 0; r < 4; ++r) {
                    int m = bm + wm + i * 16 + quad * 4 + r;
                    int n = bn + wn + t * 16 + l15;
                    int b = m >> 11, ts = m & 2047, hh = n >> 6, d = n & 63;
                    C[((size_t)((b << 4) | hh) * 2048 + wperm(ts)) * 64 + d] =
                        f2bf(sentinel(acc[i][t][r], 1e8f));
                }
    } else {
        const int b = bm >> 11;
        #pragma unroll
        for (int i = 0; i < 4; ++i) {
            int mi0 = wm + i * 16 + quad * 4;
            int colbase = ((mi0 >> 5) << 9) + ((bm & 2047) >> 2) + (mi0 & 31);
            #pragma unroll
            for (int t = 0; t < 4; ++t) {
                int n = bn + wn + t * 16 + l15;
                int hh = n >> 6, d = n & 63;
                ushort4 hv;
                hv.x = f2bf(sentinel(acc[i][t][0], 1e8f));
                hv.y = f2bf(sentinel(acc[i][t][1], 1e8f));
                hv.z = f2bf(sentinel(acc[i][t][2], 1e8f));
                hv.w = f2bf(sentinel(acc[i][t][3], 1e8f));
                *(ushort4*)&C[((size_t)((b << 4) | hh) * 64 + d) * 2048 + colbase] = hv;
            }
        }
    }
}

__global__ __launch_bounds__(256) void gemm_proj_f32(
        const ushort* __restrict__ A, const float* __restrict__ Bw,
        float* __restrict__ C)
{
    __shared__ __align__(16) ushort As[128 * 72];
    __shared__ __align__(16) ushort Bs[64 * 72];

    const int tid  = threadIdx.x;
    const int lane = tid & 63;
    const int wave = tid >> 6;
    const int quad = lane >> 4;
    const int l15  = lane & 15;
    const int bm = blockIdx.y * 128, bn = blockIdx.x * 64;
    const int wm = (wave & 1) * 64,  wn = (wave >> 1) * 32;

    f32x4 acc[4][2] = {};

    for (int k0 = 0; k0 < 1024; k0 += 64) {
        __syncthreads();
        #pragma unroll
        for (int i = 0; i < 4; ++i) {
            int c = tid + 256 * i;
            int row = c >> 3, col = (c & 7) * 8;
            int m = bm + row;
            int b = m >> 11, ts = m & 2047, h = k0 >> 6;
            size_t aoff = ((((size_t)(b * 16 + h)) * 2048 + wperm(ts)) << 6) + col;
            *(ushort8*)&As[row * 72 + col] = *(const ushort8*)&A[aoff];
        }
        #pragma unroll
        for (int i = 0; i < 4; ++i) {
            int c = tid + 256 * i;
            int row = c >> 4, col = (c & 15) * 4;
            float4 b4 = *(const float4*)&Bw[(size_t)(bn + row) * 1024 + k0 + col];
            *(ushort4*)&Bs[row * 72 + col] = cvt4(b4);
        }
        __syncthreads();

        bf16x8 af[2][4], bfr[2][2];
        #pragma unroll
        for (int f = 0; f < 2; ++f) {
            #pragma unroll
            for (int i = 0; i < 4; ++i)
                af[f][i] = *(const bf16x8*)&As[(wm + i * 16 + l15) * 72 + f * 32 + quad * 8];
            #pragma unroll
            for (int t = 0; t < 2; ++t)
                bfr[f][t] = *(const bf16x8*)&Bs[(wn + t * 16 + l15) * 72 + f * 32 + quad * 8];
        }
        #pragma unroll
        for (int f = 0; f < 2; ++f)
            #pragma unroll
            for (int i = 0; i < 4; ++i)
                #pragma unroll
                for (int t = 0; t < 2; ++t)
                    acc[i][t] = mfma16(af[f][i], bfr[f][t], acc[i][t]);
    }

    #pragma unroll
    for (int i = 0; i < 4; ++i)
        #pragma unroll
        for (int t = 0; t < 2; ++t)
            #pragma unroll
            for (int r = 0; r < 4; ++r) {
                int m = bm + wm + i * 16 + quad * 4 + r;
                int n = bn + wn + t * 16 + l15;
                C[(size_t)m * 1024 + n] = sentinel(acc[i][t][r], 100.0f);
            }
}

// ---------------------------------------------------------------------------
__global__ void diag_kernel(float* out, int n, float val) {
    int i = blockIdx.x * blockDim.x + threadIdx.x;
    if (i < n) out[i] = (i == 0) ? val : 0.f;
}

// ---------------------------------------------------------------------------
extern "C" void kernel_launch(void* const* d_in, const int* in_sizes, int n_in,
                              void* d_out, int out_size, void* d_ws, size_t ws_size,
                              hipStream_t stream) {
    const float* x  = (const float*)d_in[0];
    const float* Wq = (const float*)d_in[1];
    const float* Wk = (const float*)d_in[2];
    const float* Wv = (const float*)d_in[3];
    const float* Wp = (const float*)d_in[4];
    const int* accm = (const int*)d_in[5];
    float* out = (float*)d_out;

    const size_t SZ = (size_t)4 * 1024 * 1024;
    const size_t WSZ = (size_t)1024 * 1024;

    if (ws_size < 3 * SZ * sizeof(ushort)) {
        diag_kernel<<<(out_size + 255) / 256, 256, 0, stream>>>(
            out, out_size, (float)ws_size);
        return;
    }

    ushort* k_ws = (ushort*)d_ws;          // (b,h,t',d) world-permuted
    ushort* v_ws = k_ws + SZ;              // (b,h,d,t') TRANSPOSED, permuted
    ushort* q_ws = v_ws + SZ;              // (b,h,t',d), pre-scaled, permuted
    dim3 blk(256);

    const size_t need_fast = (4 * SZ + 4 * WSZ) * sizeof(ushort); // 40 MB
    if (ws_size >= need_fast) {
        ushort* xb  = q_ws + SZ;
        ushort* wqb = xb + SZ;
        ushort* wkb = wqb + WSZ;
        ushort* wvb = wkb + WSZ;
        ushort* wpb = wvb + WSZ;
        cvt_prepass<<<8192, blk, 0, stream>>>(x, Wq, Wk, Wv, Wp,
                                              xb, wqb, wkb, wvb, wpb);
        gemm_qkv_b<<<dim3(24, 32), blk, 0, stream>>>(xb, wqb, wkb, wvb,
                                                     q_ws, k_ws, v_ws);
        attn_kernel<<<dim3(32, 16), blk, 0, stream>>>(q_ws, k_ws, v_ws, accm);
        gemm_proj_b<<<dim3(16, 32), blk, 0, stream>>>(q_ws, wpb, out);
    } else {
        gemm_qkv_f32<<<dim3(24, 32), blk, 0, stream>>>(x, Wq, Wk, Wv,
                                                       q_ws, k_ws, v_ws);
        attn_kernel<<<dim3(32, 16), blk, 0, stream>>>(q_ws, k_ws, v_ws, accm);
        gemm_proj_f32<<<dim3(16, 32), blk, 0, stream>>>(q_ws, Wp, out);
    }
}